// Round 1
// baseline (316.994 us; speedup 1.0000x reference)
//
#include <hip/hip_runtime.h>
#include <math.h>

#define DEV __device__ __forceinline__

typedef __attribute__((ext_vector_type(4))) float f32x4;
typedef __attribute__((ext_vector_type(8))) __bf16 bf16x8;

static constexpr int Bc = 2, Sc = 2048, Dc = 1024, Hc = 16, HDc = 64;

// f32 -> bf16 bits, round-to-nearest-even
DEV unsigned short f2b(float f) {
  union { float f; unsigned int u; } c; c.f = f;
  unsigned int u = c.u;
  unsigned int r = (u + 0x7fffu + ((u >> 16) & 1u)) >> 16;
  return (unsigned short)r;
}

// async global->LDS, 16B per lane; LDS dest = wave-uniform base + lane*16
DEV void async16(const void* g, void* l) {
  __builtin_amdgcn_global_load_lds(
      (__attribute__((address_space(1))) void*)(void*)g,
      (__attribute__((address_space(3))) void*)l, 16, 0, 0);
}

__global__ void cvt_bf16(const float* __restrict__ in,
                         unsigned short* __restrict__ out, int n4) {
  int i = blockIdx.x * blockDim.x + threadIdx.x;
  if (i < n4) {
    const float4 v = reinterpret_cast<const float4*>(in)[i];
    ushort4 o;
    o.x = f2b(v.x); o.y = f2b(v.y); o.z = f2b(v.z); o.w = f2b(v.w);
    reinterpret_cast<ushort4*>(out)[i] = o;
  }
}

// C[M][N] = A[M][K] * Bm[N][K]^T + bias, bf16 inputs, OUT = ushort(bf16) or float
// 128x128 tile, BK=64, 4 waves (2x2), each wave 64x64 = 4x4 frags of 16x16x32
template <typename OUT>
__global__ __launch_bounds__(256, 2) void gemm_bt(
    const unsigned short* __restrict__ A, const unsigned short* __restrict__ Bm,
    const float* __restrict__ bias, OUT* __restrict__ C, int M, int N, int K) {
  __shared__ unsigned short As[128 * 64];
  __shared__ unsigned short Bs[128 * 64];
  const int tid = threadIdx.x;
  const int wave = tid >> 6, lane = tid & 63;
  const int wr = wave >> 1, wc = wave & 1;
  const int row0 = blockIdx.x * 128, col0 = blockIdx.y * 128;
  const int srow = lane >> 3, scol = (lane & 7) * 8;

  f32x4 acc[4][4];
#pragma unroll
  for (int m = 0; m < 4; ++m)
#pragma unroll
    for (int n = 0; n < 4; ++n) acc[m][n] = {0.f, 0.f, 0.f, 0.f};

  for (int k0 = 0; k0 < K; k0 += 64) {
    __syncthreads();
#pragma unroll
    for (int c = 0; c < 4; ++c) {
      const int rr = (wave * 4 + c) * 8 + srow;
      async16(A + (size_t)(row0 + rr) * K + k0 + scol,
              (char*)As + (wave * 4 + c) * 1024);
      async16(Bm + (size_t)(col0 + rr) * K + k0 + scol,
              (char*)Bs + (wave * 4 + c) * 1024);
    }
    __syncthreads();
#pragma unroll
    for (int ks = 0; ks < 2; ++ks) {
      const int kk = ks * 32 + (lane >> 4) * 8;
      bf16x8 af[4], bfr[4];
#pragma unroll
      for (int m = 0; m < 4; ++m)
        af[m] = *reinterpret_cast<const bf16x8*>(
            &As[(wr * 64 + m * 16 + (lane & 15)) * 64 + kk]);
#pragma unroll
      for (int n = 0; n < 4; ++n)
        bfr[n] = *reinterpret_cast<const bf16x8*>(
            &Bs[(wc * 64 + n * 16 + (lane & 15)) * 64 + kk]);
#pragma unroll
      for (int m = 0; m < 4; ++m)
#pragma unroll
        for (int n = 0; n < 4; ++n)
          acc[m][n] = __builtin_amdgcn_mfma_f32_16x16x32_bf16(af[m], bfr[n],
                                                              acc[m][n], 0, 0, 0);
    }
  }
  const int r4 = (lane >> 4) * 4, cl = lane & 15;
#pragma unroll
  for (int n = 0; n < 4; ++n) {
    const int gc = col0 + wc * 64 + n * 16 + cl;
    const float bv = bias[gc];
#pragma unroll
    for (int m = 0; m < 4; ++m) {
#pragma unroll
      for (int j = 0; j < 4; ++j) {
        const int gr = row0 + wr * 64 + m * 16 + r4 + j;
        const float v = acc[m][n][j] + bv;
        if constexpr (sizeof(OUT) == 4)
          C[(size_t)gr * N + gc] = v;
        else
          C[(size_t)gr * N + gc] = (OUT)f2b(v);
      }
    }
  }
}

// flash attention: one block = one (b,h) x 64 q-rows; 4 waves, each owns 16 rows
__global__ __launch_bounds__(256, 2) void attn_fwd(
    const unsigned short* __restrict__ Qg, const unsigned short* __restrict__ Kg,
    const unsigned short* __restrict__ Vg, const int* __restrict__ kpm,
    unsigned short* __restrict__ Og) {
  __shared__ unsigned short Qs[64 * 64];
  __shared__ unsigned short Ks[64 * 64];
  __shared__ unsigned short Vt[64 * 64];      // transposed: [d][kk]
  __shared__ unsigned short Ps[4][16 * 64];   // per-wave P tile
  __shared__ int msk[64];

  const int qb = (gridDim.x - 1) - blockIdx.x;  // heavy blocks first
  const int bh = blockIdx.y;
  const int b = bh >> 4, h = bh & 15;
  const int q0 = qb * 64;
  const int tid = threadIdx.x, wave = tid >> 6, lane = tid & 63;
  const size_t base = (size_t)b * Sc * Dc + (size_t)h * HDc;
  const int srow = lane >> 3, scol = (lane & 7) * 8;
  const int r4 = (lane >> 4) * 4, cl = lane & 15;
  const int gq0 = q0 + wave * 16 + r4;

#pragma unroll
  for (int c = 0; c < 2; ++c) {
    const int rr = (wave * 2 + c) * 8 + srow;
    async16(Qg + base + (size_t)(q0 + rr) * Dc + scol,
            (char*)Qs + (wave * 2 + c) * 1024);
  }

  float m_[4], l_[4];
  f32x4 o[4];
#pragma unroll
  for (int j = 0; j < 4; ++j) { m_[j] = -INFINITY; l_[j] = 0.f; }
#pragma unroll
  for (int n = 0; n < 4; ++n) o[n] = {0.f, 0.f, 0.f, 0.f};

  for (int kb = 0; kb <= qb; ++kb) {
    const int k0 = kb * 64;
    __syncthreads();
#pragma unroll
    for (int c = 0; c < 2; ++c) {
      const int rr = (wave * 2 + c) * 8 + srow;
      async16(Kg + base + (size_t)(k0 + rr) * Dc + scol,
              (char*)Ks + (wave * 2 + c) * 1024);
    }
    {  // V transposed into LDS: thread covers kk=tid>>2, d0=(tid&3)*16 .. +16
      const int kk = tid >> 2, d0 = (tid & 3) * 16;
      const unsigned short* vp = Vg + base + (size_t)(k0 + kk) * Dc + d0;
      union { uint4 q[2]; unsigned short u[16]; } vv;
      vv.q[0] = *reinterpret_cast<const uint4*>(vp);
      vv.q[1] = *reinterpret_cast<const uint4*>(vp + 8);
#pragma unroll
      for (int i = 0; i < 16; ++i) Vt[(d0 + i) * 64 + kk] = vv.u[i];
    }
    if (tid < 64) msk[tid] = kpm[b * Sc + k0 + tid];
    __syncthreads();

    // S = Q K^T for this wave's 16 q rows x 64 keys
    f32x4 sa[4];
#pragma unroll
    for (int n = 0; n < 4; ++n) sa[n] = {0.f, 0.f, 0.f, 0.f};
#pragma unroll
    for (int ks = 0; ks < 2; ++ks) {
      const int kk = ks * 32 + (lane >> 4) * 8;
      const bf16x8 qf =
          *reinterpret_cast<const bf16x8*>(&Qs[(wave * 16 + cl) * 64 + kk]);
#pragma unroll
      for (int n = 0; n < 4; ++n) {
        const bf16x8 kf =
            *reinterpret_cast<const bf16x8*>(&Ks[(n * 16 + cl) * 64 + kk]);
        sa[n] = __builtin_amdgcn_mfma_f32_16x16x32_bf16(qf, kf, sa[n], 0, 0, 0);
      }
    }
    // scale + masks + row max
    float pmax[4] = {-INFINITY, -INFINITY, -INFINITY, -INFINITY};
#pragma unroll
    for (int n = 0; n < 4; ++n) {
      const int gk = k0 + n * 16 + cl;
      const bool pad = msk[n * 16 + cl] != 0;
#pragma unroll
      for (int j = 0; j < 4; ++j) {
        float s = sa[n][j] * 0.125f;
        if (pad || gk > gq0 + j) s = -INFINITY;
        sa[n][j] = s;
        pmax[j] = fmaxf(pmax[j], s);
      }
    }
#pragma unroll
    for (int off = 1; off < 16; off <<= 1)
#pragma unroll
      for (int j = 0; j < 4; ++j)
        pmax[j] = fmaxf(pmax[j], __shfl_xor(pmax[j], off, 64));

    float msub[4], rs[4];
#pragma unroll
    for (int j = 0; j < 4; ++j) {
      const float mnew = fmaxf(m_[j], pmax[j]);
      msub[j] = (mnew == -INFINITY) ? 0.f : mnew;
      const float sc = expf(m_[j] - msub[j]);  // m_=-inf -> 0
      l_[j] *= sc;
#pragma unroll
      for (int n = 0; n < 4; ++n) o[n][j] *= sc;
      m_[j] = mnew;
      rs[j] = 0.f;
    }
    // P = exp(s - m), row sums, P -> LDS (bf16); per-wave region, no barrier
#pragma unroll
    for (int n = 0; n < 4; ++n) {
#pragma unroll
      for (int j = 0; j < 4; ++j) {
        const float p = expf(sa[n][j] - msub[j]);
        rs[j] += p;
        Ps[wave][(r4 + j) * 64 + n * 16 + cl] = f2b(p);
      }
    }
#pragma unroll
    for (int off = 1; off < 16; off <<= 1)
#pragma unroll
      for (int j = 0; j < 4; ++j) rs[j] += __shfl_xor(rs[j], off, 64);
#pragma unroll
    for (int j = 0; j < 4; ++j) l_[j] += rs[j];

    // O += P V
#pragma unroll
    for (int ks = 0; ks < 2; ++ks) {
      const int kk = ks * 32 + (lane >> 4) * 8;
      const bf16x8 pf =
          *reinterpret_cast<const bf16x8*>(&Ps[wave][cl * 64 + kk]);
#pragma unroll
      for (int n = 0; n < 4; ++n) {
        const bf16x8 vf =
            *reinterpret_cast<const bf16x8*>(&Vt[(n * 16 + cl) * 64 + kk]);
        o[n] = __builtin_amdgcn_mfma_f32_16x16x32_bf16(pf, vf, o[n], 0, 0, 0);
      }
    }
  }
  // finalize: O / l -> bf16 attn buffer
#pragma unroll
  for (int j = 0; j < 4; ++j) {
    const float inv = (l_[j] > 0.f) ? 1.f / l_[j] : 0.f;
#pragma unroll
    for (int n = 0; n < 4; ++n)
      Og[(size_t)(b * Sc + gq0 + j) * Dc + h * HDc + n * 16 + cl] =
          f2b(o[n][j] * inv);
  }
}

extern "C" void kernel_launch(void* const* d_in, const int* in_sizes, int n_in,
                              void* d_out, int out_size, void* d_ws,
                              size_t ws_size, hipStream_t stream) {
  const float* X = (const float*)d_in[0];
  const int* kpm = (const int*)d_in[1];
  const float* Wq = (const float*)d_in[2];
  const float* bq = (const float*)d_in[3];
  const float* Wk = (const float*)d_in[4];
  const float* bk = (const float*)d_in[5];
  const float* Wv = (const float*)d_in[6];
  const float* bv = (const float*)d_in[7];
  const float* Wo = (const float*)d_in[8];
  const float* bo = (const float*)d_in[9];
  float* out = (float*)d_out;

  char* w = (char*)d_ws;
  unsigned short* Xb = (unsigned short*)(w);                  // 8 MB
  unsigned short* Wqb = (unsigned short*)(w + (8u << 20));    // 2 MB
  unsigned short* Wkb = (unsigned short*)(w + (10u << 20));
  unsigned short* Wvb = (unsigned short*)(w + (12u << 20));
  unsigned short* Wob = (unsigned short*)(w + (14u << 20));
  unsigned short* Qb = (unsigned short*)(w + (16u << 20));    // 8 MB
  unsigned short* Kb = (unsigned short*)(w + (24u << 20));
  unsigned short* Vb = (unsigned short*)(w + (32u << 20));
  unsigned short* Ab = (unsigned short*)(w + (40u << 20));    // 8 MB -> 48 MB

  const int MD = Bc * Sc;  // 4096
  cvt_bf16<<<dim3(MD * Dc / 1024), 256, 0, stream>>>(X, Xb, MD * Dc / 4);
  cvt_bf16<<<dim3(Dc * Dc / 1024), 256, 0, stream>>>(Wq, Wqb, Dc * Dc / 4);
  cvt_bf16<<<dim3(Dc * Dc / 1024), 256, 0, stream>>>(Wk, Wkb, Dc * Dc / 4);
  cvt_bf16<<<dim3(Dc * Dc / 1024), 256, 0, stream>>>(Wv, Wvb, Dc * Dc / 4);
  cvt_bf16<<<dim3(Dc * Dc / 1024), 256, 0, stream>>>(Wo, Wob, Dc * Dc / 4);

  dim3 gg(MD / 128, Dc / 128);
  gemm_bt<unsigned short><<<gg, 256, 0, stream>>>(Xb, Wqb, bq, Qb, MD, Dc, Dc);
  gemm_bt<unsigned short><<<gg, 256, 0, stream>>>(Xb, Wkb, bk, Kb, MD, Dc, Dc);
  gemm_bt<unsigned short><<<gg, 256, 0, stream>>>(Xb, Wvb, bv, Vb, MD, Dc, Dc);

  attn_fwd<<<dim3(Sc / 64, Bc * Hc), 256, 0, stream>>>(Qb, Kb, Vb, kpm, Ab);

  gemm_bt<float><<<gg, 256, 0, stream>>>(Ab, Wob, bo, out, MD, Dc, Dc);
}

// Round 2
// 219.134 us; speedup vs baseline: 1.4466x; 1.4466x over previous
//
#include <hip/hip_runtime.h>
#include <math.h>

#define DEV __device__ __forceinline__

typedef __attribute__((ext_vector_type(4))) float f32x4;
typedef __attribute__((ext_vector_type(8))) __bf16 bf16x8;

static constexpr int Bc = 2, Sc = 2048, Dc = 1024, Hc = 16, HDc = 64;
static constexpr float SCL = 0.125f * 1.44269504f;  // 1/sqrt(64) * log2(e)

// f32 -> bf16 bits, round-to-nearest-even (used by cvt + gemm epilogue)
DEV unsigned short f2b(float f) {
  union { float f; unsigned int u; } c; c.f = f;
  unsigned int u = c.u;
  unsigned int r = (u + 0x7fffu + ((u >> 16) & 1u)) >> 16;
  return (unsigned short)r;
}

// async global->LDS, 16B per lane; LDS dest = wave-uniform base + lane*16
DEV void async16(const void* g, void* l) {
  __builtin_amdgcn_global_load_lds(
      (__attribute__((address_space(1))) void*)(void*)g,
      (__attribute__((address_space(3))) void*)l, 16, 0, 0);
}

// XOR swizzle for [R][64] bf16 tiles (128B rows): spreads banks across rows
DEV int swz(int r, int c) { return r * 64 + (c ^ ((r & 7) << 3)); }

__global__ void cvt_bf16(const float* __restrict__ in,
                         unsigned short* __restrict__ out, int n4) {
  int i = blockIdx.x * blockDim.x + threadIdx.x;
  if (i < n4) {
    const float4 v = reinterpret_cast<const float4*>(in)[i];
    ushort4 o;
    o.x = f2b(v.x); o.y = f2b(v.y); o.z = f2b(v.z); o.w = f2b(v.w);
    reinterpret_cast<ushort4*>(out)[i] = o;
  }
}

// C[M][N] = A[M][K] * Bm[N][K]^T + bias, bf16 inputs
template <typename OUT>
__global__ __launch_bounds__(256, 2) void gemm_bt(
    const unsigned short* __restrict__ A, const unsigned short* __restrict__ Bm,
    const float* __restrict__ bias, OUT* __restrict__ C, int M, int N, int K) {
  __shared__ unsigned short As[128 * 64];
  __shared__ unsigned short Bs[128 * 64];
  const int tid = threadIdx.x;
  const int wave = tid >> 6, lane = tid & 63;
  const int wr = wave >> 1, wc = wave & 1;
  const int row0 = blockIdx.x * 128, col0 = blockIdx.y * 128;
  const int srow = lane >> 3, scol = (lane & 7) * 8;

  f32x4 acc[4][4];
#pragma unroll
  for (int m = 0; m < 4; ++m)
#pragma unroll
    for (int n = 0; n < 4; ++n) acc[m][n] = {0.f, 0.f, 0.f, 0.f};

  for (int k0 = 0; k0 < K; k0 += 64) {
    __syncthreads();
#pragma unroll
    for (int c = 0; c < 4; ++c) {
      const int rr = (wave * 4 + c) * 8 + srow;
      async16(A + (size_t)(row0 + rr) * K + k0 + scol,
              (char*)As + (wave * 4 + c) * 1024);
      async16(Bm + (size_t)(col0 + rr) * K + k0 + scol,
              (char*)Bs + (wave * 4 + c) * 1024);
    }
    __syncthreads();
#pragma unroll
    for (int ks = 0; ks < 2; ++ks) {
      const int kk = ks * 32 + (lane >> 4) * 8;
      bf16x8 af[4], bfr[4];
#pragma unroll
      for (int m = 0; m < 4; ++m)
        af[m] = *reinterpret_cast<const bf16x8*>(
            &As[(wr * 64 + m * 16 + (lane & 15)) * 64 + kk]);
#pragma unroll
      for (int n = 0; n < 4; ++n)
        bfr[n] = *reinterpret_cast<const bf16x8*>(
            &Bs[(wc * 64 + n * 16 + (lane & 15)) * 64 + kk]);
#pragma unroll
      for (int m = 0; m < 4; ++m)
#pragma unroll
        for (int n = 0; n < 4; ++n)
          acc[m][n] = __builtin_amdgcn_mfma_f32_16x16x32_bf16(af[m], bfr[n],
                                                              acc[m][n], 0, 0, 0);
    }
  }
  const int r4 = (lane >> 4) * 4, cl = lane & 15;
#pragma unroll
  for (int n = 0; n < 4; ++n) {
    const int gc = col0 + wc * 64 + n * 16 + cl;
    const float bv = bias[gc];
#pragma unroll
    for (int m = 0; m < 4; ++m) {
#pragma unroll
      for (int j = 0; j < 4; ++j) {
        const int gr = row0 + wr * 64 + m * 16 + r4 + j;
        const float v = acc[m][n][j] + bv;
        if constexpr (sizeof(OUT) == 4)
          C[(size_t)gr * N + gc] = v;
        else
          C[(size_t)gr * N + gc] = (OUT)f2b(v);
      }
    }
  }
}

// flash attention: one block = one (b,h) x 64 q-rows; 4 waves, 16 rows each.
// All LDS tiles XOR-swizzled; Q hoisted to regs (its LDS reused as P tile);
// base-2 online softmax with defer-max; row-sum via MFMA vs ones-fragment.
__global__ __launch_bounds__(256, 2) void attn_fwd(
    const __bf16* __restrict__ Qg, const __bf16* __restrict__ Kg,
    const __bf16* __restrict__ Vg, const int* __restrict__ kpm,
    __bf16* __restrict__ Og) {
  __shared__ __bf16 QP[64 * 64];  // Q tile, then per-wave P tiles
  __shared__ __bf16 Ks[64 * 64];
  __shared__ __bf16 Vt[64 * 64];  // transposed: [d][k], swizzled
  __shared__ float maskf[64];

  const int qb = (gridDim.x - 1) - blockIdx.x;  // heavy blocks first
  const int bh = blockIdx.y;
  const int b = bh >> 4, h = bh & 15;
  const int q0 = qb * 64;
  const int tid = threadIdx.x, wave = tid >> 6, lane = tid & 63;
  const size_t base = (size_t)b * Sc * Dc + (size_t)h * HDc;
  const int srow = lane >> 3;
  const int scol = 8 * ((lane & 7) ^ srow);  // inverse-swizzled source col
  const int hi = lane >> 4, cl = lane & 15, r4 = hi * 4;

  // stage Q (swizzled via pre-swizzled global source)
#pragma unroll
  for (int c = 0; c < 2; ++c) {
    const int rr = (wave * 2 + c) * 8 + srow;
    async16(Qg + base + (size_t)(q0 + rr) * Dc + scol,
            (char*)QP + (wave * 2 + c) * 1024);
  }
  __syncthreads();
  bf16x8 qf[2];
#pragma unroll
  for (int ks = 0; ks < 2; ++ks)
    qf[ks] = *reinterpret_cast<const bf16x8*>(
        &QP[swz(wave * 16 + cl, ks * 32 + hi * 8)]);
  __bf16* Ps = QP + wave * 1024;  // per-wave 16x64 P tile (reuses Q LDS)

  bf16x8 ones;
#pragma unroll
  for (int i = 0; i < 8; ++i) ones[i] = (__bf16)1.0f;

  f32x4 o[4], lacc;
  float m_[4];
#pragma unroll
  for (int n = 0; n < 4; ++n) o[n] = {0.f, 0.f, 0.f, 0.f};
  lacc = {0.f, 0.f, 0.f, 0.f};
#pragma unroll
  for (int j = 0; j < 4; ++j) m_[j] = -1e30f;

  auto tile = [&](int kb, bool diag) {
    const int k0 = kb * 64;
    __syncthreads();
#pragma unroll
    for (int c = 0; c < 2; ++c) {
      const int rr = (wave * 2 + c) * 8 + srow;
      async16(Kg + base + (size_t)(k0 + rr) * Dc + scol,
              (char*)Ks + (wave * 2 + c) * 1024);
    }
    {  // V transpose into LDS (swizzled)
      const int kk = tid >> 2, d0 = (tid & 3) * 16;
      const __bf16* vp = Vg + base + (size_t)(k0 + kk) * Dc + d0;
      union { uint4 q[2]; __bf16 hv[16]; } vv;
      vv.q[0] = *reinterpret_cast<const uint4*>(vp);
      vv.q[1] = *reinterpret_cast<const uint4*>(vp + 8);
#pragma unroll
      for (int i = 0; i < 16; ++i) Vt[swz(d0 + i, kk)] = vv.hv[i];
    }
    if (tid < 64) maskf[tid] = kpm[b * Sc + k0 + tid] ? -1e30f : 0.0f;
    __syncthreads();

    // S = Q K^T
    f32x4 sa[4];
#pragma unroll
    for (int n = 0; n < 4; ++n) sa[n] = {0.f, 0.f, 0.f, 0.f};
#pragma unroll
    for (int ks = 0; ks < 2; ++ks) {
      const int kk = ks * 32 + hi * 8;
#pragma unroll
      for (int n = 0; n < 4; ++n) {
        if (!(diag && n > wave)) {  // frags fully above diagonal: skip
          const bf16x8 kf =
              *reinterpret_cast<const bf16x8*>(&Ks[swz(n * 16 + cl, kk)]);
          sa[n] = __builtin_amdgcn_mfma_f32_16x16x32_bf16(qf[ks], kf, sa[n],
                                                          0, 0, 0);
        }
      }
    }
    // scale (base-2) + additive pad mask + causal (diag only) + partial max
    float pm[4] = {-1e30f, -1e30f, -1e30f, -1e30f};
#pragma unroll
    for (int n = 0; n < 4; ++n) {
      const float mf = maskf[n * 16 + cl];
#pragma unroll
      for (int j = 0; j < 4; ++j) {
        float s2 = fmaf(sa[n][j], SCL, mf);
        if (diag && (n * 16 + cl > wave * 16 + r4 + j)) s2 = -1e30f;
        sa[n][j] = s2;
        pm[j] = fmaxf(pm[j], s2);
      }
    }
    // defer-max: only rescale when some row grew by > 8 (base-2 units)
    const bool ok = (pm[0] - m_[0] <= 8.f) && (pm[1] - m_[1] <= 8.f) &&
                    (pm[2] - m_[2] <= 8.f) && (pm[3] - m_[3] <= 8.f);
    if (!__all(ok)) {
#pragma unroll
      for (int off = 1; off < 16; off <<= 1)
#pragma unroll
        for (int j = 0; j < 4; ++j)
          pm[j] = fmaxf(pm[j], __shfl_xor(pm[j], off, 64));
#pragma unroll
      for (int j = 0; j < 4; ++j) {
        const float mn = fmaxf(m_[j], pm[j]);
        const float sc = __builtin_amdgcn_exp2f(m_[j] - mn);
        m_[j] = mn;
        lacc[j] *= sc;
#pragma unroll
        for (int n = 0; n < 4; ++n) o[n][j] *= sc;
      }
    }
    // P = 2^(s2 - m) -> LDS (bf16, swizzled); bounded by 2^8
#pragma unroll
    for (int n = 0; n < 4; ++n)
#pragma unroll
      for (int j = 0; j < 4; ++j) {
        const float p = __builtin_amdgcn_exp2f(sa[n][j] - m_[j]);
        Ps[swz(r4 + j, n * 16 + cl)] = (__bf16)p;
      }
    // O += P V ; l += P * 1 (row sums on the matrix pipe)
#pragma unroll
    for (int ks = 0; ks < 2; ++ks) {
      const int kk = ks * 32 + hi * 8;
      const bf16x8 pf = *reinterpret_cast<const bf16x8*>(&Ps[swz(cl, kk)]);
#pragma unroll
      for (int n = 0; n < 4; ++n) {
        const bf16x8 vf =
            *reinterpret_cast<const bf16x8*>(&Vt[swz(n * 16 + cl, kk)]);
        o[n] = __builtin_amdgcn_mfma_f32_16x16x32_bf16(pf, vf, o[n], 0, 0, 0);
      }
      lacc = __builtin_amdgcn_mfma_f32_16x16x32_bf16(pf, ones, lacc, 0, 0, 0);
    }
  };

  for (int kb = 0; kb < qb; ++kb) tile(kb, false);
  tile(qb, true);

#pragma unroll
  for (int j = 0; j < 4; ++j) {
    const float inv = 1.f / lacc[j];
#pragma unroll
    for (int n = 0; n < 4; ++n)
      Og[(size_t)(b * Sc + q0 + wave * 16 + r4 + j) * Dc + h * HDc + n * 16 +
         cl] = (__bf16)(o[n][j] * inv);
  }
}

extern "C" void kernel_launch(void* const* d_in, const int* in_sizes, int n_in,
                              void* d_out, int out_size, void* d_ws,
                              size_t ws_size, hipStream_t stream) {
  const float* X = (const float*)d_in[0];
  const int* kpm = (const int*)d_in[1];
  const float* Wq = (const float*)d_in[2];
  const float* bq = (const float*)d_in[3];
  const float* Wk = (const float*)d_in[4];
  const float* bk = (const float*)d_in[5];
  const float* Wv = (const float*)d_in[6];
  const float* bv = (const float*)d_in[7];
  const float* Wo = (const float*)d_in[8];
  const float* bo = (const float*)d_in[9];
  float* out = (float*)d_out;

  char* w = (char*)d_ws;
  unsigned short* Xb = (unsigned short*)(w);                  // 8 MB
  unsigned short* Wqb = (unsigned short*)(w + (8u << 20));    // 2 MB
  unsigned short* Wkb = (unsigned short*)(w + (10u << 20));
  unsigned short* Wvb = (unsigned short*)(w + (12u << 20));
  unsigned short* Wob = (unsigned short*)(w + (14u << 20));
  unsigned short* Qb = (unsigned short*)(w + (16u << 20));    // 8 MB
  unsigned short* Kb = (unsigned short*)(w + (24u << 20));
  unsigned short* Vb = (unsigned short*)(w + (32u << 20));
  unsigned short* Ab = (unsigned short*)(w + (40u << 20));    // 8 MB -> 48 MB

  const int MD = Bc * Sc;  // 4096
  cvt_bf16<<<dim3(MD * Dc / 1024), 256, 0, stream>>>(X, Xb, MD * Dc / 4);
  cvt_bf16<<<dim3(Dc * Dc / 1024), 256, 0, stream>>>(Wq, Wqb, Dc * Dc / 4);
  cvt_bf16<<<dim3(Dc * Dc / 1024), 256, 0, stream>>>(Wk, Wkb, Dc * Dc / 4);
  cvt_bf16<<<dim3(Dc * Dc / 1024), 256, 0, stream>>>(Wv, Wvb, Dc * Dc / 4);
  cvt_bf16<<<dim3(Dc * Dc / 1024), 256, 0, stream>>>(Wo, Wob, Dc * Dc / 4);

  dim3 gg(MD / 128, Dc / 128);
  gemm_bt<unsigned short><<<gg, 256, 0, stream>>>(Xb, Wqb, bq, Qb, MD, Dc, Dc);
  gemm_bt<unsigned short><<<gg, 256, 0, stream>>>(Xb, Wkb, bk, Kb, MD, Dc, Dc);
  gemm_bt<unsigned short><<<gg, 256, 0, stream>>>(Xb, Wvb, bv, Vb, MD, Dc, Dc);

  attn_fwd<<<dim3(Sc / 64, Bc * Hc), 256, 0, stream>>>(
      (const __bf16*)Qb, (const __bf16*)Kb, (const __bf16*)Vb, kpm,
      (__bf16*)Ab);

  gemm_bt<float><<<gg, 256, 0, stream>>>(Ab, Wob, bo, out, MD, Dc, Dc);
}

// Round 3
// 142.650 us; speedup vs baseline: 2.2222x; 1.5362x over previous
//
#include <hip/hip_runtime.h>
#include <math.h>

#define DEV __device__ __forceinline__

typedef __attribute__((ext_vector_type(4))) float f32x4;
typedef __attribute__((ext_vector_type(8))) __bf16 bf16x8;

static constexpr int Bc = 2, Sc = 2048, Dc = 1024, Hc = 16, HDc = 64;
static constexpr int LDQ = 3 * Dc;                  // fused QKV row stride
static constexpr float SCL = 0.125f * 1.44269504f;  // 1/sqrt(64) * log2(e)

// f32 -> bf16 bits, round-to-nearest-even
DEV unsigned short f2b(float f) {
  union { float f; unsigned int u; } c; c.f = f;
  unsigned int u = c.u;
  unsigned int r = (u + 0x7fffu + ((u >> 16) & 1u)) >> 16;
  return (unsigned short)r;
}

// async global->LDS, 16B per lane; LDS dest = wave-uniform base + lane*16
DEV void async16(const void* g, void* l) {
  __builtin_amdgcn_global_load_lds(
      (__attribute__((address_space(1))) void*)(void*)g,
      (__attribute__((address_space(3))) void*)l, 16, 0, 0);
}

// XOR swizzle for [R][64] bf16 tiles (128B rows)
DEV int swz(int r, int c) { return r * 64 + (c ^ ((r & 7) << 3)); }

__global__ void cvt_x(const float* __restrict__ in,
                      unsigned short* __restrict__ out, int n4) {
  int i = blockIdx.x * blockDim.x + threadIdx.x;
  if (i < n4) {
    const float4 v = reinterpret_cast<const float4*>(in)[i];
    ushort4 o;
    o.x = f2b(v.x); o.y = f2b(v.y); o.z = f2b(v.z); o.w = f2b(v.w);
    reinterpret_cast<ushort4*>(out)[i] = o;
  }
}

// all four weight matrices in one launch; blockIdx.y selects the source
__global__ void cvt_w(const float* __restrict__ w0, const float* __restrict__ w1,
                      const float* __restrict__ w2, const float* __restrict__ w3,
                      unsigned short* __restrict__ out) {
  const float* src = blockIdx.y == 0 ? w0
                     : blockIdx.y == 1 ? w1
                     : blockIdx.y == 2 ? w2 : w3;
  const int i = blockIdx.x * blockDim.x + threadIdx.x;
  const float4 v = reinterpret_cast<const float4*>(src)[i];
  ushort4 o;
  o.x = f2b(v.x); o.y = f2b(v.y); o.z = f2b(v.z); o.w = f2b(v.w);
  reinterpret_cast<ushort4*>(out)[(size_t)blockIdx.y * (Dc * Dc / 4) + i] = o;
}

// C[M][*] = A[M][K] * Bm[*][K]^T + bias; bias selected per 1024-col group.
template <typename OUT>
__global__ __launch_bounds__(256, 2) void gemm_bt(
    const unsigned short* __restrict__ A, const unsigned short* __restrict__ Bm,
    const float* __restrict__ b0, const float* __restrict__ b1,
    const float* __restrict__ b2, OUT* __restrict__ C, int M, int K, int ldc) {
  __shared__ unsigned short As[128 * 64];
  __shared__ unsigned short Bs[128 * 64];
  const int tid = threadIdx.x;
  const int wave = tid >> 6, lane = tid & 63;
  const int wr = wave >> 1, wc = wave & 1;
  const int row0 = blockIdx.x * 128, col0 = blockIdx.y * 128;
  const int srow = lane >> 3, scol = (lane & 7) * 8;

  f32x4 acc[4][4];
#pragma unroll
  for (int m = 0; m < 4; ++m)
#pragma unroll
    for (int n = 0; n < 4; ++n) acc[m][n] = {0.f, 0.f, 0.f, 0.f};

  for (int k0 = 0; k0 < K; k0 += 64) {
    __syncthreads();
#pragma unroll
    for (int c = 0; c < 4; ++c) {
      const int rr = (wave * 4 + c) * 8 + srow;
      async16(A + (size_t)(row0 + rr) * K + k0 + scol,
              (char*)As + (wave * 4 + c) * 1024);
      async16(Bm + (size_t)(col0 + rr) * K + k0 + scol,
              (char*)Bs + (wave * 4 + c) * 1024);
    }
    __syncthreads();
#pragma unroll
    for (int ks = 0; ks < 2; ++ks) {
      const int kk = ks * 32 + (lane >> 4) * 8;
      bf16x8 af[4], bfr[4];
#pragma unroll
      for (int m = 0; m < 4; ++m)
        af[m] = *reinterpret_cast<const bf16x8*>(
            &As[(wr * 64 + m * 16 + (lane & 15)) * 64 + kk]);
#pragma unroll
      for (int n = 0; n < 4; ++n)
        bfr[n] = *reinterpret_cast<const bf16x8*>(
            &Bs[(wc * 64 + n * 16 + (lane & 15)) * 64 + kk]);
#pragma unroll
      for (int m = 0; m < 4; ++m)
#pragma unroll
        for (int n = 0; n < 4; ++n)
          acc[m][n] = __builtin_amdgcn_mfma_f32_16x16x32_bf16(af[m], bfr[n],
                                                              acc[m][n], 0, 0, 0);
    }
  }
  const int r4 = (lane >> 4) * 4, cl = lane & 15;
#pragma unroll
  for (int n = 0; n < 4; ++n) {
    const int gc = col0 + wc * 64 + n * 16 + cl;
    const float* bp = gc < Dc ? b0 : (gc < 2 * Dc ? b1 : b2);
    const float bv = bp[gc & (Dc - 1)];
#pragma unroll
    for (int m = 0; m < 4; ++m) {
#pragma unroll
      for (int j = 0; j < 4; ++j) {
        const int gr = row0 + wr * 64 + m * 16 + r4 + j;
        const float v = acc[m][n][j] + bv;
        if constexpr (sizeof(OUT) == 4)
          C[(size_t)gr * ldc + gc] = v;
        else
          C[(size_t)gr * ldc + gc] = (OUT)f2b(v);
      }
    }
  }
}

// flash attention, 2-phase pipelined: issue next K(async)+V(reg) stage before
// computing the current tile; V written to LDS after PV; one barrier per tile.
__global__ __launch_bounds__(256, 4) void attn_fwd(
    const __bf16* __restrict__ Qg, const __bf16* __restrict__ Kg,
    const __bf16* __restrict__ Vg, const int* __restrict__ kpm,
    __bf16* __restrict__ Og) {
  __shared__ __bf16 QP[64 * 64];     // Q tile, reused as per-wave P tiles
  __shared__ __bf16 Ks[2][64 * 64];  // double-buffered K
  __shared__ __bf16 Vt[2][64 * 64];  // double-buffered V^T [d][k]

  const int qb = (gridDim.x - 1) - blockIdx.x;  // heavy blocks first
  const int bh = blockIdx.y;
  const int b = bh >> 4, h = bh & 15;
  const int q0 = qb * 64;
  const int tid = threadIdx.x, wave = tid >> 6, lane = tid & 63;
  const size_t base = (size_t)b * Sc * LDQ + (size_t)h * HDc;
  const int srow = lane >> 3;
  const int scol = 8 * ((lane & 7) ^ srow);  // inverse-swizzled source col
  const int hi = lane >> 4, cl = lane & 15, r4 = hi * 4;

  // V loader: 2 k-rows x 8 d per thread; packed b32 swizzled writes
  const int vk2 = (tid & 31) * 2, vd8 = (tid >> 5) * 8;
  const __bf16* vbase = Vg + base + (size_t)vk2 * LDQ + vd8;
  const int* mbase = kpm + b * Sc;

  union VV { uint4 q; unsigned short u[8]; };

  // prologue: stage Q + K0 (async), V0 + mask0 (regs)
#pragma unroll
  for (int c = 0; c < 2; ++c) {
    const int rr = (wave * 2 + c) * 8 + srow;
    async16(Qg + base + (size_t)(q0 + rr) * LDQ + scol,
            (char*)QP + (wave * 2 + c) * 1024);
    async16(Kg + base + (size_t)rr * LDQ + scol,
            (char*)Ks[0] + (wave * 2 + c) * 1024);
  }
  VV v0, v1;
  v0.q = *reinterpret_cast<const uint4*>(vbase);
  v1.q = *reinterpret_cast<const uint4*>(vbase + LDQ);
  int mki[4];
#pragma unroll
  for (int n = 0; n < 4; ++n) mki[n] = mbase[n * 16 + cl];
  {
    unsigned int* V32 = reinterpret_cast<unsigned int*>(Vt[0]);
#pragma unroll
    for (int i = 0; i < 8; ++i) {
      const int row = vd8 + i;
      V32[row * 32 + ((tid & 31) ^ ((row & 7) << 2))] =
          (unsigned int)v0.u[i] | ((unsigned int)v1.u[i] << 16);
    }
  }
  __syncthreads();

  bf16x8 qf[2];
#pragma unroll
  for (int ks = 0; ks < 2; ++ks)
    qf[ks] = *reinterpret_cast<const bf16x8*>(
        &QP[swz(wave * 16 + cl, ks * 32 + hi * 8)]);
  __bf16* Ps = QP + wave * 1024;  // per-wave 16x64 P tile

  bf16x8 ones;
#pragma unroll
  for (int i = 0; i < 8; ++i) ones[i] = (__bf16)1.0f;

  f32x4 o[4], lacc;
  float m_[4];
#pragma unroll
  for (int n = 0; n < 4; ++n) o[n] = {0.f, 0.f, 0.f, 0.f};
  lacc = {0.f, 0.f, 0.f, 0.f};
#pragma unroll
  for (int j = 0; j < 4; ++j) m_[j] = -1e30f;

  int pb = 0;
  for (int kb = 0; kb <= qb; ++kb) {
    const bool diag = (kb == qb);  // last tile is the diagonal tile
    VV n0, n1;
    int nmk[4];
    if (!diag) {  // issue next tile's stage FIRST (hides under compute)
      const int k1 = (kb + 1) * 64;
#pragma unroll
      for (int c = 0; c < 2; ++c) {
        const int rr = (wave * 2 + c) * 8 + srow;
        async16(Kg + base + (size_t)(k1 + rr) * LDQ + scol,
                (char*)Ks[pb ^ 1] + (wave * 2 + c) * 1024);
      }
      n0.q = *reinterpret_cast<const uint4*>(vbase + (size_t)k1 * LDQ);
      n1.q = *reinterpret_cast<const uint4*>(vbase + (size_t)(k1 + 1) * LDQ);
#pragma unroll
      for (int n = 0; n < 4; ++n) nmk[n] = mbase[k1 + n * 16 + cl];
    }

    // S = Q K^T from Ks[pb]
    f32x4 sa[4];
#pragma unroll
    for (int n = 0; n < 4; ++n) sa[n] = {0.f, 0.f, 0.f, 0.f};
#pragma unroll
    for (int ks = 0; ks < 2; ++ks) {
      const int kk = ks * 32 + hi * 8;
#pragma unroll
      for (int n = 0; n < 4; ++n) {
        if (!(diag && n > wave)) {  // frags fully above diagonal: skip
          const bf16x8 kf = *reinterpret_cast<const bf16x8*>(
              &Ks[pb][swz(n * 16 + cl, kk)]);
          sa[n] = __builtin_amdgcn_mfma_f32_16x16x32_bf16(qf[ks], kf, sa[n],
                                                          0, 0, 0);
        }
      }
    }
    // scale (base-2) + pad mask + causal (diag only) + partial max
    float pm[4] = {-1e30f, -1e30f, -1e30f, -1e30f};
#pragma unroll
    for (int n = 0; n < 4; ++n) {
      const float mf = mki[n] ? -1e30f : 0.0f;
#pragma unroll
      for (int j = 0; j < 4; ++j) {
        float s2 = fmaf(sa[n][j], SCL, mf);
        if (diag && (n * 16 + cl > wave * 16 + r4 + j)) s2 = -1e30f;
        sa[n][j] = s2;
        pm[j] = fmaxf(pm[j], s2);
      }
    }
    // defer-max: rescale only when some row grew by > 8 (base-2 units)
    const bool ok = (pm[0] - m_[0] <= 8.f) && (pm[1] - m_[1] <= 8.f) &&
                    (pm[2] - m_[2] <= 8.f) && (pm[3] - m_[3] <= 8.f);
    if (!__all(ok)) {
#pragma unroll
      for (int off = 1; off < 16; off <<= 1)
#pragma unroll
        for (int j = 0; j < 4; ++j)
          pm[j] = fmaxf(pm[j], __shfl_xor(pm[j], off, 64));
#pragma unroll
      for (int j = 0; j < 4; ++j) {
        const float mn = fmaxf(m_[j], pm[j]);
        const float sc = __builtin_amdgcn_exp2f(m_[j] - mn);
        m_[j] = mn;
        lacc[j] *= sc;
#pragma unroll
        for (int n = 0; n < 4; ++n) o[n][j] *= sc;
      }
    }
    // P = 2^(s2 - m) -> per-wave LDS tile
#pragma unroll
    for (int n = 0; n < 4; ++n)
#pragma unroll
      for (int j = 0; j < 4; ++j) {
        const float p = __builtin_amdgcn_exp2f(sa[n][j] - m_[j]);
        Ps[swz(r4 + j, n * 16 + cl)] = (__bf16)p;
      }
    // O += P V ; l += P * 1
#pragma unroll
    for (int ks = 0; ks < 2; ++ks) {
      const int kk = ks * 32 + hi * 8;
      const bf16x8 pf = *reinterpret_cast<const bf16x8*>(&Ps[swz(cl, kk)]);
#pragma unroll
      for (int n = 0; n < 4; ++n) {
        const bf16x8 vf = *reinterpret_cast<const bf16x8*>(
            &Vt[pb][swz(n * 16 + cl, kk)]);
        o[n] = __builtin_amdgcn_mfma_f32_16x16x32_bf16(pf, vf, o[n], 0, 0, 0);
      }
      lacc = __builtin_amdgcn_mfma_f32_16x16x32_bf16(pf, ones, lacc, 0, 0, 0);
    }
    // write next V (loads had the whole tile to land) + rotate mask
    if (!diag) {
      unsigned int* V32 = reinterpret_cast<unsigned int*>(Vt[pb ^ 1]);
#pragma unroll
      for (int i = 0; i < 8; ++i) {
        const int row = vd8 + i;
        V32[row * 32 + ((tid & 31) ^ ((row & 7) << 2))] =
            (unsigned int)n0.u[i] | ((unsigned int)n1.u[i] << 16);
      }
#pragma unroll
      for (int n = 0; n < 4; ++n) mki[n] = nmk[n];
    }
    __syncthreads();  // drains K-async (vmcnt) + V ds_writes (lgkm)
    pb ^= 1;
  }

#pragma unroll
  for (int j = 0; j < 4; ++j) {
    const float inv = 1.f / lacc[j];
#pragma unroll
    for (int n = 0; n < 4; ++n)
      Og[(size_t)(b * Sc + q0 + wave * 16 + r4 + j) * Dc + h * HDc + n * 16 +
         cl] = (__bf16)(o[n][j] * inv);
  }
}

extern "C" void kernel_launch(void* const* d_in, const int* in_sizes, int n_in,
                              void* d_out, int out_size, void* d_ws,
                              size_t ws_size, hipStream_t stream) {
  const float* X = (const float*)d_in[0];
  const int* kpm = (const int*)d_in[1];
  const float* Wq = (const float*)d_in[2];
  const float* bq = (const float*)d_in[3];
  const float* Wk = (const float*)d_in[4];
  const float* bk = (const float*)d_in[5];
  const float* Wv = (const float*)d_in[6];
  const float* bv = (const float*)d_in[7];
  const float* Wo = (const float*)d_in[8];
  const float* bo = (const float*)d_in[9];
  float* out = (float*)d_out;

  char* w = (char*)d_ws;
  unsigned short* Xb = (unsigned short*)(w);                  // 8 MB
  unsigned short* Wqkvb = (unsigned short*)(w + (8u << 20));  // 6 MB (q,k,v)
  unsigned short* Wob = (unsigned short*)(w + (14u << 20));   // 2 MB
  unsigned short* QKVb = (unsigned short*)(w + (16u << 20));  // 24 MB
  unsigned short* Ab = (unsigned short*)(w + (40u << 20));    // 8 MB -> 48 MB

  const int MD = Bc * Sc;  // 4096
  cvt_x<<<dim3(MD * Dc / 1024), 256, 0, stream>>>(X, Xb, MD * Dc / 4);
  cvt_w<<<dim3(Dc * Dc / 1024, 4), 256, 0, stream>>>(Wq, Wk, Wv, Wo, Wqkvb);

  // fused QKV projection: C is [4096][3072]
  gemm_bt<unsigned short><<<dim3(MD / 128, LDQ / 128), 256, 0, stream>>>(
      Xb, Wqkvb, bq, bk, bv, QKVb, MD, Dc, LDQ);

  attn_fwd<<<dim3(Sc / 64, Bc * Hc), 256, 0, stream>>>(
      (const __bf16*)QKVb, (const __bf16*)QKVb + Dc,
      (const __bf16*)QKVb + 2 * Dc, kpm, (__bf16*)Ab);

  gemm_bt<float><<<dim3(MD / 128, Dc / 128), 256, 0, stream>>>(
      Ab, Wob, bo, bo, bo, out, MD, Dc, Dc);
}